// Round 8
// baseline (344.336 us; speedup 1.0000x reference)
//
#include <hip/hip_runtime.h>
#include <hip/hip_bf16.h>
#include <math.h>

typedef unsigned int  uint;
typedef unsigned short ushort;

// Problem constants
#define DD    256      // embedding dim
#define KK    2048     // num codewords
#define HW    1024     // H*W
#define NN    32768    // rows
#define NUMEL 8388608  // total elements
#define STRIDEB (DD*HW)
#define NBLK_QL (NUMEL/1024)   // 8192 quant_loss blocks

// Workspace layout (bytes)
#define WS_H2     0         // 2048 f32: 0.5*||e_k||^2
#define WS_COUNTS 8192      // 2048 i32
#define WS_EBF    16512     // emb frag-ordered bf16 hi/lo: 2 MB
#define WS_BPART  2113664   // 8192 f32 loss block partials

// Output layout (floats): quantized_st | loss | perplexity | indices(as float)
#define OUT_LOSS  8388608
#define OUT_PPL   8388609
#define OUT_IDX   8388610

typedef __attribute__((ext_vector_type(8))) short  short8;   // 8 bf16 (4 VGPR)
typedef __attribute__((ext_vector_type(4))) float  float4v;  // 4 fp32 acc

__device__ __forceinline__ ushort f2bf(float f) {   // RNE fp32->bf16 bits
    uint u = __float_as_uint(f);
    return (ushort)((u + 0x7FFFu + ((u >> 16) & 1u)) >> 16);
}

// --------------------------------------------------------------------------
// Kernel 1: h2[k] = 0.5*sum_d emb[d][k]^2; zero the histogram.
__global__ __launch_bounds__(256) void e2h_kernel(const float* __restrict__ emb,
                                                  float* __restrict__ h2,
                                                  int*   __restrict__ counts) {
    int k = blockIdx.x * 256 + threadIdx.x;
    float s = 0.f;
    for (int d = 0; d < DD; ++d) {
        float v = emb[(size_t)d * KK + k];
        s += v * v;
    }
    h2[k] = 0.5f * s;
    counts[k] = 0;
}

// --------------------------------------------------------------------------
// Kernel 2: reorder emb (D,K) fp32 into MFMA-B-fragment-major bf16 hi/lo.
__global__ __launch_bounds__(256) void prep_emb(const float* __restrict__ emb,
                                                ushort* __restrict__ ebf) {
    int g  = blockIdx.x * 256 + threadIdx.x;
    int k  = g & (KK - 1);
    int dg = g >> 11;          // 0..31
    int d0 = dg * 8;
    int s    = dg >> 2;
    int quad = dg & 3;
    int ct   = k >> 4;
    int l    = quad * 16 + (k & 15);

    union { ushort us[8]; uint4 v; } hu, lu;
#pragma unroll
    for (int j = 0; j < 8; ++j) {
        float v = emb[(size_t)(d0 + j) * KK + k];
        ushort hb = f2bf(v);
        float  hf = __uint_as_float(((uint)hb) << 16);
        hu.us[j] = hb;
        lu.us[j] = f2bf(v - hf);
    }
    size_t hi_off = (size_t)(((ct * 8 + s) * 2 + 0) * 64 + l) * 8;
    size_t lo_off = (size_t)(((ct * 8 + s) * 2 + 1) * 64 + l) * 8;
    *(uint4*)(ebf + hi_off) = hu.v;
    *(uint4*)(ebf + lo_off) = lu.v;
}

// --------------------------------------------------------------------------
// Kernel 3: split-bf16 MFMA distance + per-row argmin over ALL 2048 cols.
// v7 (global-direct): NO LDS, NO global_load_lds, NO barriers in the K-loop.
// R7 post-mortem: six schedule variants (occupancy x2, counted vmcnt, LDS
// traffic x1/2, barrier groups x2) ALL pinned at MfmaUtil 37-40% -> the
// serialization is the staging pattern itself: compiler cannot prove the
// DMA dest and ds_read src don't alias, so an effective vmcnt drain lands
// on the critical path EVERY tile regardless of schedule (~2500 cyc serial
// vs 1862 cyc MFMA = 40%). Fix: read B-fragments straight from global into
// registers. ebf (2 MB) is L2-resident; 4 waves/block read the same tile
// within a short window -> L1 serves most re-reads. Waves free-run: the 2
// waves/SIMD anti-phase so one's MFMA burst hides the other's load wait
// (m114 mechanism at instruction granularity, no barriers to lockstep).
// Each wave now scans all 128 column tiles -> merge_kernel deleted.
__global__ __launch_bounds__(256, 2) void argmin_mfma(
    const float*  __restrict__ x,
    const ushort* __restrict__ ebf,
    const float*  __restrict__ h2,
    float* __restrict__ out_idx_f,
    int*   __restrict__ counts)
{
    const int tid  = threadIdx.x;
    const int w    = tid >> 6;
    const int lane = tid & 63;
    const int m    = lane & 15;
    const int quad = lane >> 4;

    const int n0  = blockIdx.x * 128 + w * 32;   // wave's first row (32 rows)
    const int b   = n0 >> 10;                    // 128 | 1024: no straddle
    const int hwb = n0 & 1023;
    const float* xb = x + (size_t)b * STRIDEB;

    // A fragments in registers: 2 strips x 8 slices x (hi,lo) = 128 VGPRs.
    short8 xh[2][8], xl[2][8];
#pragma unroll
    for (int st = 0; st < 2; ++st) {
        const int hw = hwb + st * 16 + m;
#pragma unroll
        for (int s = 0; s < 8; ++s) {
            const float* p = xb + (size_t)(s * 32 + quad * 8) * HW + hw;
            short8 hh, ll;
#pragma unroll
            for (int j = 0; j < 8; ++j) {
                float v = p[(size_t)j * HW];
                v = fminf(fmaxf(v, -10.f), 10.f);
                ushort hb = f2bf(v);
                float  hf = __uint_as_float(((uint)hb) << 16);
                hh[j] = (short)hb;
                ll[j] = (short)f2bf(v - hf);
            }
            xh[st][s] = hh;
            xl[st][s] = ll;
        }
    }

    float bv[2][4] = {{1e30f,1e30f,1e30f,1e30f},{1e30f,1e30f,1e30f,1e30f}};
    int   bi[2][4] = {{0,0,0,0},{0,0,0,0}};

    // Per-lane fragment pointer for tile 0: 1 KB-coalesced short8 loads.
    const short8* fp = (const short8*)ebf + lane;   // + (s*2+hl)*64 per frag

    for (int ct = 0; ct < 128; ++ct) {
        // Load the 16 B-fragments of this tile (global -> VGPR, L1/L2-hit).
        short8 eh[8], el[8];
#pragma unroll
        for (int s = 0; s < 8; ++s) {
            eh[s] = fp[(s * 2 + 0) * 64];
            el[s] = fp[(s * 2 + 1) * 64];
        }
        const float hv = h2[ct * 16 + m];     // 8 KB, L1-resident

        float4v ahh0 = {0,0,0,0}, ahl0 = {0,0,0,0}, alh0 = {0,0,0,0};
        float4v ahh1 = {0,0,0,0}, ahl1 = {0,0,0,0}, alh1 = {0,0,0,0};
#pragma unroll
        for (int s = 0; s < 8; ++s) {
            alh0 = __builtin_amdgcn_mfma_f32_16x16x32_bf16(xl[0][s], eh[s], alh0, 0, 0, 0);
            ahl0 = __builtin_amdgcn_mfma_f32_16x16x32_bf16(xh[0][s], el[s], ahl0, 0, 0, 0);
            ahh0 = __builtin_amdgcn_mfma_f32_16x16x32_bf16(xh[0][s], eh[s], ahh0, 0, 0, 0);
            alh1 = __builtin_amdgcn_mfma_f32_16x16x32_bf16(xl[1][s], eh[s], alh1, 0, 0, 0);
            ahl1 = __builtin_amdgcn_mfma_f32_16x16x32_bf16(xh[1][s], el[s], ahl1, 0, 0, 0);
            ahh1 = __builtin_amdgcn_mfma_f32_16x16x32_bf16(xh[1][s], eh[s], ahh1, 0, 0, 0);
        }
        const int c = ct * 16 + m;
#pragma unroll
        for (int i = 0; i < 4; ++i) {
            float s0 = hv - (ahh0[i] + (ahl0[i] + alh0[i]));
            float s1 = hv - (ahh1[i] + (ahl1[i] + alh1[i]));
            if (s0 < bv[0][i]) { bv[0][i] = s0; bi[0][i] = c; }
            if (s1 < bv[1][i]) { bv[1][i] = s1; bi[1][i] = c; }
        }
        fp += 1024;   // next 16 KB tile (1024 short8)
    }

    // Cross-lane argmin fold (over the 16 m-lanes); lowest index on ties —
    // matches jnp.argmin first-min semantics (ascending ct scan + strict <).
#pragma unroll
    for (int st = 0; st < 2; ++st) {
#pragma unroll
        for (int i = 0; i < 4; ++i) {
            float v  = bv[st][i];
            int   ix = bi[st][i];
#pragma unroll
            for (int msk = 8; msk >= 1; msk >>= 1) {
                float ov = __shfl_xor(v, msk, 64);
                int   oi = __shfl_xor(ix, msk, 64);
                if (ov < v || (ov == v && oi < ix)) { v = ov; ix = oi; }
            }
            if (m == 0) {
                int n = n0 + st * 16 + quad * 4 + i;
                ix = min(max(ix, 0), KK - 1);
                out_idx_f[n] = (float)ix;
                atomicAdd(&counts[ix], 1);
            }
        }
    }
}

// --------------------------------------------------------------------------
// Kernel 5: gather quantized values + MSE reduction. NO global atomics:
// per-wave shfl reduce -> LDS -> one plain store per block (bpart[bid]).
__global__ __launch_bounds__(256) void quant_loss_kernel(
    const float* __restrict__ x,
    const float* __restrict__ emb,
    const float* __restrict__ idxf,
    float* __restrict__ outq,
    float* __restrict__ bpart)
{
    __shared__ float red[4];
    size_t o4 = ((size_t)blockIdx.x * 256 + threadIdx.x) * 4;
    int b  = (int)(o4 >> 18);
    int d  = (int)((o4 >> 10) & 255);
    int n  = b * HW + (int)(o4 & 1023);
    int i0 = (int)idxf[n + 0];
    int i1 = (int)idxf[n + 1];
    int i2 = (int)idxf[n + 2];
    int i3 = (int)idxf[n + 3];
    i0 = min(max(i0, 0), KK - 1); i1 = min(max(i1, 0), KK - 1);
    i2 = min(max(i2, 0), KK - 1); i3 = min(max(i3, 0), KK - 1);
    const float* er = emb + (size_t)d * KK;
    float4 q;
    q.x = er[i0]; q.y = er[i1]; q.z = er[i2]; q.w = er[i3];
    const float4 xv = *(const float4*)(x + o4);
    *(float4*)(outq + o4) = q;
    float ax = q.x - xv.x, ay = q.y - xv.y, az = q.z - xv.z, aw = q.w - xv.w;
    float s = ax * ax + ay * ay + az * az + aw * aw;
#pragma unroll
    for (int off = 32; off > 0; off >>= 1) s += __shfl_down(s, off, 64);
    if ((threadIdx.x & 63) == 0) red[threadIdx.x >> 6] = s;
    __syncthreads();
    if (threadIdx.x == 0)
        bpart[blockIdx.x] = red[0] + red[1] + red[2] + red[3];
}

// --------------------------------------------------------------------------
// Kernel 6: perplexity from histogram + loss from block partials.
__global__ __launch_bounds__(256) void finalize_kernel(
    const int* __restrict__ counts,
    const float* __restrict__ bpart,
    float* __restrict__ out)
{
    __shared__ float redp[4], redl[4];
    int tid = threadIdx.x;
    float s = 0.f;
    for (int k = tid; k < KK; k += 256) {
        float p = (float)counts[k] * (1.0f / (float)NN);
        s += p * logf(p + 1e-10f);
    }
    float ls = 0.f;
    for (int k = tid; k < NBLK_QL; k += 256) ls += bpart[k];
#pragma unroll
    for (int off = 32; off > 0; off >>= 1) {
        s  += __shfl_down(s, off, 64);
        ls += __shfl_down(ls, off, 64);
    }
    if ((tid & 63) == 0) { redp[tid >> 6] = s; redl[tid >> 6] = ls; }
    __syncthreads();
    if (tid == 0) {
        float tot = redp[0] + redp[1] + redp[2] + redp[3];
        float lsum = redl[0] + redl[1] + redl[2] + redl[3];
        out[OUT_PPL]  = expf(-tot);
        out[OUT_LOSS] = lsum * 1.25f / (float)NUMEL;
    }
}

// --------------------------------------------------------------------------
extern "C" void kernel_launch(void* const* d_in, const int* in_sizes, int n_in,
                              void* d_out, int out_size, void* d_ws, size_t ws_size,
                              hipStream_t stream) {
    const float* x   = (const float*)d_in[0];
    const float* emb = (const float*)d_in[1];
    float* out = (float*)d_out;
    char*  ws  = (char*)d_ws;

    float*  h2     = (float*)(ws + WS_H2);
    int*    counts = (int*)(ws + WS_COUNTS);
    ushort* ebf    = (ushort*)(ws + WS_EBF);
    float*  bpart  = (float*)(ws + WS_BPART);

    e2h_kernel<<<KK / 256, 256, 0, stream>>>(emb, h2, counts);
    prep_emb<<<256, 256, 0, stream>>>(emb, ebf);
    argmin_mfma<<<NN / 128, 256, 0, stream>>>(x, ebf, h2, out + OUT_IDX, counts);
    quant_loss_kernel<<<NBLK_QL, 256, 0, stream>>>(x, emb, out + OUT_IDX, out, bpart);
    finalize_kernel<<<1, 256, 0, stream>>>(counts, bpart, out);
}

// Round 9
// 207.592 us; speedup vs baseline: 1.6587x; 1.6587x over previous
//
#include <hip/hip_runtime.h>
#include <hip/hip_bf16.h>
#include <math.h>

typedef unsigned int  uint;
typedef unsigned short ushort;

// Problem constants
#define DD    256      // embedding dim
#define KK    2048     // num codewords
#define HW    1024     // H*W
#define NN    32768    // rows
#define NUMEL 8388608  // total elements
#define STRIDEB (DD*HW)
#define NBLK_QL (NUMEL/1024)   // 8192 quant_loss blocks

// Workspace layout (bytes) — total ~2.67 MB
#define WS_H2     0         // 2048 f32: 0.5*||e_k||^2
#define WS_COUNTS 8192      // 2048 i32
#define WS_EBF    16512     // emb frag-ordered bf16 hi/lo: 2 MB
#define WS_PV     2113664   // 65536 f32 partial best value  (N x 2 halves)
#define WS_PI     2375808   // 65536 i32 partial best index
#define WS_BPART  2637952   // 8192 f32 loss partials (pv now read by quant -> no alias)

// Output layout (floats): quantized_st | loss | perplexity | indices(as float)
#define OUT_LOSS  8388608
#define OUT_PPL   8388609
#define OUT_IDX   8388610

typedef __attribute__((ext_vector_type(8))) short  short8;   // 8 bf16 (4 VGPR)
typedef __attribute__((ext_vector_type(4))) float  float4v;  // 4 fp32 acc

typedef __attribute__((address_space(1))) uint guint;  // global
typedef __attribute__((address_space(3))) uint luint;  // LDS

__device__ __forceinline__ ushort f2bf(float f) {   // RNE fp32->bf16 bits
    uint u = __float_as_uint(f);
    return (ushort)((u + 0x7FFFu + ((u >> 16) & 1u)) >> 16);
}

// --------------------------------------------------------------------------
// Kernel 1: reorder emb (D,K) fp32 into MFMA-B-fragment-major bf16 hi/lo,
// AND accumulate h2[k] = 0.5*sum_d emb[d][k]^2 (R8 tail fix: e2h deleted —
// it ran 2048 threads x 256 serial loads on 8 CUs; here every element is
// already in registers. 65536 atomics over 2048 addrs, lanes hit distinct
// addrs -> no intra-wave contention. h2/counts zeroed by hipMemsetAsync.)
__global__ __launch_bounds__(256) void prep_emb(const float* __restrict__ emb,
                                                ushort* __restrict__ ebf,
                                                float* __restrict__ h2) {
    int g  = blockIdx.x * 256 + threadIdx.x;
    int k  = g & (KK - 1);
    int dg = g >> 11;          // 0..31
    int d0 = dg * 8;
    int s    = dg >> 2;
    int quad = dg & 3;
    int ct   = k >> 4;
    int l    = quad * 16 + (k & 15);

    union { ushort us[8]; uint4 v; } hu, lu;
    float p2 = 0.f;
#pragma unroll
    for (int j = 0; j < 8; ++j) {
        float v = emb[(size_t)(d0 + j) * KK + k];
        p2 += v * v;
        ushort hb = f2bf(v);
        float  hf = __uint_as_float(((uint)hb) << 16);
        hu.us[j] = hb;
        lu.us[j] = f2bf(v - hf);
    }
    size_t hi_off = (size_t)(((ct * 8 + s) * 2 + 0) * 64 + l) * 8;
    size_t lo_off = (size_t)(((ct * 8 + s) * 2 + 1) * 64 + l) * 8;
    *(uint4*)(ebf + hi_off) = hu.v;
    *(uint4*)(ebf + lo_off) = lu.v;
    atomicAdd(&h2[k], 0.5f * p2);
}

// --------------------------------------------------------------------------
// Kernel 2: split-bf16 MFMA distance + per-row argmin over a column half.
// EXACT v2 revert (R1: 108.4 us, MfmaUtil 40% — best of 7 measured
// variants). Ledger: occupancy 2->4 w/SIMD null (R3); counted vmcnt -9%
// (R4/R5); 4 barrier groups null (R7); LDS traffic x0.5 null; global-
// direct -95% (R8). All pipes ~45-50% at 3-4 w/SIMD -> latency-bound
// steady state; 108 us = 46% of the 50 us MFMA floor is this structure's
// ceiling. Do not re-iterate the schedule without asm-level evidence.
__global__ __launch_bounds__(256, 2) void argmin_mfma(
    const float*  __restrict__ x,
    const ushort* __restrict__ ebf,
    const float*  __restrict__ h2,
    float* __restrict__ pv,
    int*   __restrict__ pi)
{
    __shared__ ushort sB[2][8192];   // 2 x 16 KB tile double-buffer
    __shared__ float  sH2[1024];     // 4 KB: h2 for this column half

    const int tid  = threadIdx.x;
    const int w    = tid >> 6;
    const int lane = tid & 63;
    const int m    = lane & 15;
    const int quad = lane >> 4;

    const int rb = blockIdx.x >> 1;
    const int ch = blockIdx.x & 1;
    const int n0 = rb * 128 + w * 32;          // wave's first row
    const int b  = n0 >> 10;
    const int hwb = n0 & 1023;
    const float* xb = x + (size_t)b * STRIDEB;
    const int cbase = ch * 1024;
    const int ctg0  = cbase >> 4;

    auto stage = [&](ushort* dst, int ctg) {
        const char* gs = (const char*)(ebf + (size_t)ctg * 8192) + tid * 16;
        char*       ls = (char*)dst + tid * 16;
#pragma unroll
        for (int i = 0; i < 4; ++i)
            __builtin_amdgcn_global_load_lds((guint*)(gs + i * 4096),
                                             (luint*)(ls + i * 4096),
                                             16, 0, 0);
    };

    stage(sB[0], ctg0);
    ((float4*)sH2)[tid] = ((const float4*)(h2 + cbase))[tid];

    // A fragments in registers: 2 strips x 8 slices x (hi,lo).
    short8 xh[2][8], xl[2][8];
#pragma unroll
    for (int st = 0; st < 2; ++st) {
        const int hw = hwb + st * 16 + m;
#pragma unroll
        for (int s = 0; s < 8; ++s) {
            const float* p = xb + (size_t)(s * 32 + quad * 8) * HW + hw;
            short8 hh, ll;
#pragma unroll
            for (int j = 0; j < 8; ++j) {
                float v = p[(size_t)j * HW];
                v = fminf(fmaxf(v, -10.f), 10.f);
                ushort hb = f2bf(v);
                float  hf = __uint_as_float(((uint)hb) << 16);
                hh[j] = (short)hb;
                ll[j] = (short)f2bf(v - hf);
            }
            xh[st][s] = hh;
            xl[st][s] = ll;
        }
    }

    float bv[2][4] = {{1e30f,1e30f,1e30f,1e30f},{1e30f,1e30f,1e30f,1e30f}};
    int   bi[2][4] = {{0,0,0,0},{0,0,0,0}};

    auto compute_tile = [&](const ushort* sbc, int ct) {
        float4v ahh0 = {0,0,0,0}, ahl0 = {0,0,0,0}, alh0 = {0,0,0,0};
        float4v ahh1 = {0,0,0,0}, ahl1 = {0,0,0,0}, alh1 = {0,0,0,0};
#pragma unroll
        for (int s = 0; s < 8; ++s) {
            short8 eh = *(const short8*)&sbc[(s * 2 + 0) * 512 + lane * 8];
            short8 el = *(const short8*)&sbc[(s * 2 + 1) * 512 + lane * 8];
            alh0 = __builtin_amdgcn_mfma_f32_16x16x32_bf16(xl[0][s], eh, alh0, 0, 0, 0);
            ahl0 = __builtin_amdgcn_mfma_f32_16x16x32_bf16(xh[0][s], el, ahl0, 0, 0, 0);
            ahh0 = __builtin_amdgcn_mfma_f32_16x16x32_bf16(xh[0][s], eh, ahh0, 0, 0, 0);
            alh1 = __builtin_amdgcn_mfma_f32_16x16x32_bf16(xl[1][s], eh, alh1, 0, 0, 0);
            ahl1 = __builtin_amdgcn_mfma_f32_16x16x32_bf16(xh[1][s], el, ahl1, 0, 0, 0);
            ahh1 = __builtin_amdgcn_mfma_f32_16x16x32_bf16(xh[1][s], eh, ahh1, 0, 0, 0);
        }
        const int c  = cbase + ct * 16 + m;
        const float hv = sH2[ct * 16 + m];
#pragma unroll
        for (int i = 0; i < 4; ++i) {
            float s0 = hv - (ahh0[i] + (ahl0[i] + alh0[i]));
            float s1 = hv - (ahh1[i] + (ahl1[i] + alh1[i]));
            if (s0 < bv[0][i]) { bv[0][i] = s0; bi[0][i] = c; }
            if (s1 < bv[1][i]) { bv[1][i] = s1; bi[1][i] = c; }
        }
    };

    __syncthreads();   // drains tile-0 DMA (vmcnt) + sH2 write (lgkmcnt)

    for (int ct = 0; ct < 64; ct += 2) {
        stage(sB[1], ctg0 + ct + 1);
        compute_tile(sB[0], ct);
        __syncthreads();
        stage(sB[0], (ct + 2 < 64) ? (ctg0 + ct + 2) : ctg0);
        compute_tile(sB[1], ct + 1);
        __syncthreads();
    }

#pragma unroll
    for (int st = 0; st < 2; ++st) {
#pragma unroll
        for (int i = 0; i < 4; ++i) {
            float v  = bv[st][i];
            int   ix = bi[st][i];
#pragma unroll
            for (int msk = 8; msk >= 1; msk >>= 1) {
                float ov = __shfl_xor(v, msk, 64);
                int   oi = __shfl_xor(ix, msk, 64);
                if (ov < v || (ov == v && oi < ix)) { v = ov; ix = oi; }
            }
            if (m == 0) {
                int n = n0 + st * 16 + quad * 4 + i;
                pv[n * 2 + ch] = v;
                pi[n * 2 + ch] = ix;
            }
        }
    }
}

// --------------------------------------------------------------------------
// Kernel 3: fused merge + gather + MSE + histogram (R8 tail fix: the old
// merge_kernel launch is deleted; pv/pi are 512 KB = L2-resident, so each
// block re-merging its 1024 rows costs ~0 HBM. The 32 blocks with d==0
// write out_idx and the histogram exactly once per n.)
__global__ __launch_bounds__(256) void quant_loss_kernel(
    const float* __restrict__ x,
    const float* __restrict__ emb,
    const float* __restrict__ pv,
    const int*   __restrict__ pi,
    float* __restrict__ out_idx_f,
    int*   __restrict__ counts,
    float* __restrict__ outq,
    float* __restrict__ bpart)
{
    __shared__ float red[4];
    size_t o4 = ((size_t)blockIdx.x * 256 + threadIdx.x) * 4;
    int b  = (int)(o4 >> 18);
    int d  = (int)((o4 >> 10) & 255);
    int n  = b * HW + (int)(o4 & 1023);

    // Re-merge the two column halves for n..n+3 (strict <, half-0 on ties —
    // identical to the old merge_kernel).
    const float4* pv4 = (const float4*)(pv + (size_t)n * 2);
    const int4*   pi4 = (const int4*)(pi + (size_t)n * 2);
    float4 pva = pv4[0], pvb = pv4[1];
    int4   pia = pi4[0], pib = pi4[1];
    int i0 = (pva.y < pva.x) ? pia.y : pia.x;
    int i1 = (pva.w < pva.z) ? pia.w : pia.z;
    int i2 = (pvb.y < pvb.x) ? pib.y : pib.x;
    int i3 = (pvb.w < pvb.z) ? pib.w : pib.z;
    i0 = min(max(i0, 0), KK - 1); i1 = min(max(i1, 0), KK - 1);
    i2 = min(max(i2, 0), KK - 1); i3 = min(max(i3, 0), KK - 1);

    if (d == 0) {   // one writer per n: emit index + histogram
        float4 ixf = { (float)i0, (float)i1, (float)i2, (float)i3 };
        *(float4*)(out_idx_f + n) = ixf;
        atomicAdd(&counts[i0], 1);
        atomicAdd(&counts[i1], 1);
        atomicAdd(&counts[i2], 1);
        atomicAdd(&counts[i3], 1);
    }

    const float* er = emb + (size_t)d * KK;
    float4 q;
    q.x = er[i0]; q.y = er[i1]; q.z = er[i2]; q.w = er[i3];
    const float4 xv = *(const float4*)(x + o4);
    *(float4*)(outq + o4) = q;
    float ax = q.x - xv.x, ay = q.y - xv.y, az = q.z - xv.z, aw = q.w - xv.w;
    float s = ax * ax + ay * ay + az * az + aw * aw;
#pragma unroll
    for (int off = 32; off > 0; off >>= 1) s += __shfl_down(s, off, 64);
    if ((threadIdx.x & 63) == 0) red[threadIdx.x >> 6] = s;
    __syncthreads();
    if (threadIdx.x == 0)
        bpart[blockIdx.x] = red[0] + red[1] + red[2] + red[3];
}

// --------------------------------------------------------------------------
// Kernel 4: perplexity from histogram + loss from block partials.
__global__ __launch_bounds__(256) void finalize_kernel(
    const int* __restrict__ counts,
    const float* __restrict__ bpart,
    float* __restrict__ out)
{
    __shared__ float redp[4], redl[4];
    int tid = threadIdx.x;
    float s = 0.f;
    for (int k = tid; k < KK; k += 256) {
        float p = (float)counts[k] * (1.0f / (float)NN);
        s += p * logf(p + 1e-10f);
    }
    float ls = 0.f;
    for (int k = tid; k < NBLK_QL; k += 256) ls += bpart[k];
#pragma unroll
    for (int off = 32; off > 0; off >>= 1) {
        s  += __shfl_down(s, off, 64);
        ls += __shfl_down(ls, off, 64);
    }
    if ((tid & 63) == 0) { redp[tid >> 6] = s; redl[tid >> 6] = ls; }
    __syncthreads();
    if (tid == 0) {
        float tot = redp[0] + redp[1] + redp[2] + redp[3];
        float lsum = redl[0] + redl[1] + redl[2] + redl[3];
        out[OUT_PPL]  = expf(-tot);
        out[OUT_LOSS] = lsum * 1.25f / (float)NUMEL;
    }
}

// --------------------------------------------------------------------------
extern "C" void kernel_launch(void* const* d_in, const int* in_sizes, int n_in,
                              void* d_out, int out_size, void* d_ws, size_t ws_size,
                              hipStream_t stream) {
    const float* x   = (const float*)d_in[0];
    const float* emb = (const float*)d_in[1];
    float* out = (float*)d_out;
    char*  ws  = (char*)d_ws;

    float*  h2     = (float*)(ws + WS_H2);
    int*    counts = (int*)(ws + WS_COUNTS);
    ushort* ebf    = (ushort*)(ws + WS_EBF);
    float*  pv     = (float*)(ws + WS_PV);
    int*    pi     = (int*)(ws + WS_PI);
    float*  bpart  = (float*)(ws + WS_BPART);

    hipMemsetAsync(ws, 0, 16384, stream);   // h2 + counts
    prep_emb<<<256, 256, 0, stream>>>(emb, ebf, h2);
    argmin_mfma<<<512, 256, 0, stream>>>(x, ebf, h2, pv, pi);
    quant_loss_kernel<<<NBLK_QL, 256, 0, stream>>>(x, emb, pv, pi,
                                                   out + OUT_IDX, counts, out, bpart);
    finalize_kernel<<<1, 256, 0, stream>>>(counts, bpart, out);
}